// Round 3
// baseline (514.839 us; speedup 1.0000x reference)
//
#include <hip/hip_runtime.h>

typedef __attribute__((ext_vector_type(4))) float f32x4;
typedef __attribute__((ext_vector_type(8))) short bf16x8;

#define EPS_ 1e-5f
// SCALE * log2(e): fold exp -> exp2 into the q scaling
#define QSC 0.25503639409729144f

// LDS: X/obuf [64][256] bf16, XOR-swizzled (16B-slot ^= row&7) = 32 KB. Nothing else.
// -> LDS allows 5 blocks/CU; VGPR (cap 170 via launch_bounds(256,3)) gives >=3 blocks
//    = >=12 waves/CU (vs 8 before). All q/k/P/vT LDS round-trips replaced by
//    in-register quad-fold transposes (ds_bpermute).
#define LDS_BYTES 32768

__device__ __forceinline__ int swzx(int r, int c) { return r * 256 + (c ^ ((r & 7) << 3)); }

__device__ __forceinline__ unsigned int pack2(float a, float b) {
  union { float f; unsigned int u; } ua, ub;
  ua.f = a; ub.f = b;
  unsigned int ra = (ua.u + 0x7FFFu + ((ua.u >> 16) & 1u)) >> 16;
  unsigned int rb = (ub.u + 0x7FFFu + ((ub.u >> 16) & 1u)) & 0xFFFF0000u;
  return ra | rb;
}
__device__ __forceinline__ uint2 pack4(f32x4 v) {
  uint2 o; o.x = pack2(v[0], v[1]); o.y = pack2(v[2], v[3]); return o;
}
__device__ __forceinline__ unsigned short f2b(float f) {
  union { float f; unsigned int u; } c; c.f = f;
  return (unsigned short)((c.u + 0x7FFFu + ((c.u >> 16) & 1u)) >> 16);
}

// Quad-fold transpose: C-layout accs (A0: ch 0-15 = quad*4+r, A1: ch 16-31) ->
// A/B fragment (lane quad Q holds ch = Q*8 + 2j+b in u32 reg j).
// Derivation: ch'=8Q+2j+b -> src m2 = Q>>1, src reg = (2j+b)&3,
// src quad = (2Q + (j>>1)) & 3. 8 bpermute + 4 pack + 4 select.
__device__ __forceinline__ bf16x8 xform(f32x4 A0, f32x4 A1, int ae, int ao, bool hi) {
  int P0 = (int)pack2(A0[0], A0[1]), P1 = (int)pack2(A0[2], A0[3]);
  int P2 = (int)pack2(A1[0], A1[1]), P3 = (int)pack2(A1[2], A1[3]);
  int e0 = __builtin_amdgcn_ds_bpermute(ae, P0);
  int e1 = __builtin_amdgcn_ds_bpermute(ae, P1);
  int e2 = __builtin_amdgcn_ds_bpermute(ae, P2);
  int e3 = __builtin_amdgcn_ds_bpermute(ae, P3);
  int o0 = __builtin_amdgcn_ds_bpermute(ao, P0);
  int o1 = __builtin_amdgcn_ds_bpermute(ao, P1);
  int o2 = __builtin_amdgcn_ds_bpermute(ao, P2);
  int o3 = __builtin_amdgcn_ds_bpermute(ao, P3);
  union { bf16x8 v; int u[4]; } r;
  r.u[0] = hi ? e2 : e0;
  r.u[1] = hi ? e3 : e1;
  r.u[2] = hi ? o2 : o0;
  r.u[3] = hi ? o3 : o1;
  return r.v;
}

// K0: fp32 weights -> bf16, [Wq|Wk|Wv|Wp] each 256x256.
__global__ __launch_bounds__(256) void k0_cvt(const float* __restrict__ w0,
                                              const float* __restrict__ w1,
                                              const float* __restrict__ w2,
                                              const float* __restrict__ w3,
                                              unsigned short* __restrict__ dst) {
  int idx = blockIdx.x * 256 + threadIdx.x;
  const float* s = (blockIdx.y == 0) ? w0 : (blockIdx.y == 1) ? w1 : (blockIdx.y == 2) ? w2 : w3;
  dst[blockIdx.y * 65536 + idx] = f2b(s[idx]);
}

// KA: one window per 256-thread block; wave wv owns heads {2wv, 2wv+1}.
// Attention entirely in registers (bpermute transposes); LDS only for the
// shared X tile / obuf. 3 barriers.
__global__ __launch_bounds__(256, 3) void ka_fused(
    const unsigned short* __restrict__ Wall,
    const float* __restrict__ ln_g, const float* __restrict__ ln_b,
    const int* __restrict__ pn, const int* __restrict__ pt,
    const float* __restrict__ bq, const float* __restrict__ bk,
    const float* __restrict__ bv, const float* __restrict__ bp,
    const float* __restrict__ inpt, float* __restrict__ out) {
  extern __shared__ unsigned short lds[];

  const int tid = threadIdx.x;
  const int wv = tid >> 6, lane = tid & 63, quad = lane >> 4, l15 = lane & 15;
  const int w = blockIdx.x;
  const int b = w >> 9, nbb = (w >> 6) & 7, tbb = w & 63;
  const f32x4 z4 = {0.f, 0.f, 0.f, 0.f};

  // bpermute source-lane addresses for the quad-fold (byte units)
  const int ae = ((((quad << 1) & 3) << 4) + l15) << 2;
  const int ao = (((((quad << 1) + 1) & 3) << 4) + l15) << 2;
  const bool hi = lane >= 32;

  // ---- fused gather + LayerNorm -> bf16 X tile (16 rows per wave) ----
  {
    const float4 gg = ((const float4*)ln_g)[lane];
    const float4 bb = ((const float4*)ln_b)[lane];
    #pragma unroll
    for (int ii = 0; ii < 2; ++ii) {
      const int nloc = wv * 2 + ii;
      const int spn = pn[(b << 6) + (nbb << 3) + nloc];
      const float* rowbase = inpt + (size_t)((b << 6) + spn) * 512 * 256;
      float4 v[8];
      #pragma unroll
      for (int i = 0; i < 8; ++i) {
        const int spt = pt[(b << 9) + (tbb << 3) + i];
        v[i] = ((const float4*)(rowbase + (size_t)spt * 256))[lane];
      }
      #pragma unroll
      for (int i = 0; i < 8; ++i) {
        float s = v[i].x + v[i].y + v[i].z + v[i].w;
        float ss = v[i].x * v[i].x + v[i].y * v[i].y + v[i].z * v[i].z + v[i].w * v[i].w;
        #pragma unroll
        for (int m = 1; m < 64; m <<= 1) { s += __shfl_xor(s, m); ss += __shfl_xor(ss, m); }
        const float mean = s * (1.0f / 256.0f);
        const float rs = rsqrtf(ss * (1.0f / 256.0f) - mean * mean + EPS_);
        ushort4 o;
        o.x = f2b((v[i].x - mean) * rs * gg.x + bb.x);
        o.y = f2b((v[i].y - mean) * rs * gg.y + bb.y);
        o.z = f2b((v[i].z - mean) * rs * gg.z + bb.z);
        o.w = f2b((v[i].w - mean) * rs * gg.w + bb.w);
        const int row = nloc * 8 + i;
        *(ushort4*)(lds + swzx(row, lane * 4)) = o;
      }
    }
  }
  __syncthreads();

  const unsigned short* Wq = Wall;
  const unsigned short* Wk = Wall + 65536;
  const unsigned short* Wv_ = Wall + 131072;
  const unsigned short* Wp = Wall + 196608;

  uint2 opk[2][2][4];  // per-head packed O held in regs until obuf barrier

  #pragma unroll
  for (int hh = 0; hh < 2; ++hh) {
    const int h = (wv << 1) + hh;

    // ---- QKV for head h: Q^T,K^T = W·X^T ; V = X·Wv^T ----
    f32x4 qa[2][4], ka_[2][4], va[4][2];
    #pragma unroll
    for (int m2 = 0; m2 < 2; ++m2)
      #pragma unroll
      for (int nt = 0; nt < 4; ++nt) { qa[m2][nt] = z4; ka_[m2][nt] = z4; }
    #pragma unroll
    for (int mt = 0; mt < 4; ++mt)
      #pragma unroll
      for (int m2 = 0; m2 < 2; ++m2) va[mt][m2] = z4;

    #pragma unroll
    for (int ks = 0; ks < 8; ++ks) {
      bf16x8 bx[4];
      #pragma unroll
      for (int nt = 0; nt < 4; ++nt)
        bx[nt] = *(const bf16x8*)(lds + swzx(nt * 16 + l15, ks * 32 + quad * 8));
      #pragma unroll
      for (int m2 = 0; m2 < 2; ++m2) {
        const int wrow = (h * 32 + m2 * 16 + l15) * 256 + ks * 32 + quad * 8;
        bf16x8 wq8 = *(const bf16x8*)(Wq + wrow);
        bf16x8 wk8 = *(const bf16x8*)(Wk + wrow);
        bf16x8 wv8 = *(const bf16x8*)(Wv_ + wrow);
        #pragma unroll
        for (int nt = 0; nt < 4; ++nt) {
          qa[m2][nt] = __builtin_amdgcn_mfma_f32_16x16x32_bf16(wq8, bx[nt], qa[m2][nt], 0, 0, 0);
          ka_[m2][nt] = __builtin_amdgcn_mfma_f32_16x16x32_bf16(wk8, bx[nt], ka_[m2][nt], 0, 0, 0);
          va[nt][m2] = __builtin_amdgcn_mfma_f32_16x16x32_bf16(bx[nt], wv8, va[nt][m2], 0, 0, 0);
        }
      }
    }

    // ---- bias (+scale for q) applied in C-layout ----
    #pragma unroll
    for (int m2 = 0; m2 < 2; ++m2) {
      const float4 bq4 = ((const float4*)(bq + h * 32 + m2 * 16))[quad];
      const float4 bk4 = ((const float4*)(bk + h * 32 + m2 * 16))[quad];
      const float bvv = bv[h * 32 + m2 * 16 + l15];
      #pragma unroll
      for (int nt = 0; nt < 4; ++nt) {
        qa[m2][nt][0] = (qa[m2][nt][0] + bq4.x) * QSC;
        qa[m2][nt][1] = (qa[m2][nt][1] + bq4.y) * QSC;
        qa[m2][nt][2] = (qa[m2][nt][2] + bq4.z) * QSC;
        qa[m2][nt][3] = (qa[m2][nt][3] + bq4.w) * QSC;
        ka_[m2][nt][0] += bk4.x; ka_[m2][nt][1] += bk4.y;
        ka_[m2][nt][2] += bk4.z; ka_[m2][nt][3] += bk4.w;
        va[nt][m2][0] += bvv; va[nt][m2][1] += bvv;
        va[nt][m2][2] += bvv; va[nt][m2][3] += bvv;
      }
    }

    // ---- in-register transposes: C-layout -> MFMA fragments ----
    bf16x8 qf[4], kf[4], vf[2][2];
    #pragma unroll
    for (int i = 0; i < 4; ++i) qf[i] = xform(qa[0][i], qa[1][i], ae, ao, hi);
    #pragma unroll
    for (int i = 0; i < 4; ++i) kf[i] = xform(ka_[0][i], ka_[1][i], ae, ao, hi);
    #pragma unroll
    for (int kk = 0; kk < 2; ++kk)
      #pragma unroll
      for (int m2 = 0; m2 < 2; ++m2)
        vf[kk][m2] = xform(va[2 * kk][m2], va[2 * kk + 1][m2], ae, ao, hi);

    // ---- S^T = k·q^T, exp2, pack P-hat fragments (normalization deferred to O) ----
    float tot[4] = {0.f, 0.f, 0.f, 0.f};
    bf16x8 pb[2][4];
    #pragma unroll
    for (int kk = 0; kk < 2; ++kk)
      #pragma unroll
      for (int ntq = 0; ntq < 4; ++ntq) {
        f32x4 s0 = __builtin_amdgcn_mfma_f32_16x16x32_bf16(kf[2 * kk], qf[ntq], z4, 0, 0, 0);
        f32x4 s1 = __builtin_amdgcn_mfma_f32_16x16x32_bf16(kf[2 * kk + 1], qf[ntq], z4, 0, 0, 0);
        #pragma unroll
        for (int r = 0; r < 4; ++r) {
          s0[r] = __builtin_amdgcn_exp2f(s0[r]); tot[ntq] += s0[r];
          s1[r] = __builtin_amdgcn_exp2f(s1[r]); tot[ntq] += s1[r];
        }
        pb[kk][ntq] = xform(s0, s1, ae, ao, hi);
      }
    float inv[4];
    #pragma unroll
    for (int ntq = 0; ntq < 4; ++ntq) {
      float t = tot[ntq];
      t += __shfl_xor(t, 16);
      t += __shfl_xor(t, 32);
      inv[ntq] = 1.0f / t;
    }

    // ---- O^T = V^T·P-hat^T, then scale by inv (softmax denominator) ----
    #pragma unroll
    for (int m2 = 0; m2 < 2; ++m2)
      #pragma unroll
      for (int ntq = 0; ntq < 4; ++ntq) {
        f32x4 oa = __builtin_amdgcn_mfma_f32_16x16x32_bf16(vf[0][m2], pb[0][ntq], z4, 0, 0, 0);
        oa = __builtin_amdgcn_mfma_f32_16x16x32_bf16(vf[1][m2], pb[1][ntq], oa, 0, 0, 0);
        oa[0] *= inv[ntq]; oa[1] *= inv[ntq]; oa[2] *= inv[ntq]; oa[3] *= inv[ntq];
        opk[hh][m2][ntq] = pack4(oa);
      }
  }

  __syncthreads();  // all waves done reading X (both heads)
  #pragma unroll
  for (int hh = 0; hh < 2; ++hh)
    #pragma unroll
    for (int m2 = 0; m2 < 2; ++m2)
      #pragma unroll
      for (int ntq = 0; ntq < 4; ++ntq)
        *(uint2*)(lds + swzx(ntq * 16 + l15, ((wv * 2 + hh) * 32 + m2 * 16 + quad * 4))) =
            opk[hh][m2][ntq];
  __syncthreads();  // obuf ready

  // ---- proj^T = Wp·O^T : wave owns out-channels [wv*64, wv*64+64) ----
  f32x4 pacc[4][4];
  #pragma unroll
  for (int m4 = 0; m4 < 4; ++m4)
    #pragma unroll
    for (int nto = 0; nto < 4; ++nto) pacc[m4][nto] = z4;
  #pragma unroll
  for (int ks = 0; ks < 8; ++ks) {
    bf16x8 ob[4];
    #pragma unroll
    for (int nto = 0; nto < 4; ++nto)
      ob[nto] = *(const bf16x8*)(lds + swzx(nto * 16 + l15, ks * 32 + quad * 8));
    #pragma unroll
    for (int m4 = 0; m4 < 4; ++m4) {
      bf16x8 wp8 = *(const bf16x8*)(Wp + (wv * 64 + m4 * 16 + l15) * 256 + ks * 32 + quad * 8);
      #pragma unroll
      for (int nto = 0; nto < 4; ++nto)
        pacc[m4][nto] = __builtin_amdgcn_mfma_f32_16x16x32_bf16(wp8, ob[nto], pacc[m4][nto], 0, 0, 0);
    }
  }

  // ---- epilogue: +bp, residual, float4 scatter (col=tok, row=och) ----
  int toff[4];
  #pragma unroll
  for (int nto = 0; nto < 4; ++nto) {
    const int tok = nto * 16 + l15;
    const int n = (nbb << 3) + (tok >> 3), t = (tbb << 3) + (tok & 7);
    toff[nto] = (((b << 6) + pn[(b << 6) + n]) * 512 + pt[(b << 9) + t]) * 256;
  }
  #pragma unroll
  for (int m4 = 0; m4 < 4; ++m4) {
    float4 bp4 = ((const float4*)(bp + wv * 64 + m4 * 16))[quad];
    #pragma unroll
    for (int nto = 0; nto < 4; ++nto) {
      const int off = toff[nto] + wv * 64 + m4 * 16 + quad * 4;
      float4 iv = *(const float4*)(inpt + off);
      float4 o;
      o.x = iv.x + pacc[m4][nto][0] + bp4.x;
      o.y = iv.y + pacc[m4][nto][1] + bp4.y;
      o.z = iv.z + pacc[m4][nto][2] + bp4.z;
      o.w = iv.w + pacc[m4][nto][3] + bp4.w;
      *(float4*)(out + off) = o;
    }
  }
}

extern "C" void kernel_launch(void* const* d_in, const int* in_sizes, int n_in,
                              void* d_out, int out_size, void* d_ws, size_t ws_size,
                              hipStream_t stream) {
  const float* inpt = (const float*)d_in[0];
  const int* perm_n = (const int*)d_in[1];
  const int* perm_t = (const int*)d_in[2];
  const float* ln_g = (const float*)d_in[3];
  const float* ln_b = (const float*)d_in[4];
  const float* Wq = (const float*)d_in[5];
  const float* bq = (const float*)d_in[6];
  const float* Wk = (const float*)d_in[7];
  const float* bk = (const float*)d_in[8];
  const float* Wv = (const float*)d_in[9];
  const float* bv = (const float*)d_in[10];
  const float* Wp = (const float*)d_in[11];
  const float* bp = (const float*)d_in[12];
  float* out = (float*)d_out;

  // ws: Wall (512 KiB) only
  unsigned short* Wall = (unsigned short*)d_ws;

  (void)hipFuncSetAttribute((const void*)ka_fused,
                            hipFuncAttributeMaxDynamicSharedMemorySize, LDS_BYTES);

  k0_cvt<<<dim3(256, 4), 256, 0, stream>>>(Wq, Wk, Wv, Wp, Wall);
  ka_fused<<<2048, 256, LDS_BYTES, stream>>>(Wall, ln_g, ln_b, perm_n, perm_t,
                                             bq, bk, bv, bp, inpt, out);
}

// Round 4
// 409.957 us; speedup vs baseline: 1.2558x; 1.2558x over previous
//
#include <hip/hip_runtime.h>

typedef __attribute__((ext_vector_type(4))) float f32x4;
typedef __attribute__((ext_vector_type(8))) short bf16x8;

#define EPS_ 1e-5f
// SCALE * log2(e): fold exp -> exp2 into the q scaling
#define QSC 0.25503639409729144f

// LDS: X/obuf [64][256] bf16, XOR-swizzled (16B-slot ^= row&7) = 32 KB. Nothing else.
// Two-pass QKV keeps peak accumulator pressure ~130 VGPR (no spill at cap 170):
//   pass1: K,V accumulators (64) -> kf/vf fragments; pass2: Q (32) -> qf.
#define LDS_BYTES 32768

__device__ __forceinline__ int swzx(int r, int c) { return r * 256 + (c ^ ((r & 7) << 3)); }

__device__ __forceinline__ unsigned int pack2(float a, float b) {
  union { float f; unsigned int u; } ua, ub;
  ua.f = a; ub.f = b;
  unsigned int ra = (ua.u + 0x7FFFu + ((ua.u >> 16) & 1u)) >> 16;
  unsigned int rb = (ub.u + 0x7FFFu + ((ub.u >> 16) & 1u)) & 0xFFFF0000u;
  return ra | rb;
}
__device__ __forceinline__ uint2 pack4(f32x4 v) {
  uint2 o; o.x = pack2(v[0], v[1]); o.y = pack2(v[2], v[3]); return o;
}
__device__ __forceinline__ unsigned short f2b(float f) {
  union { float f; unsigned int u; } c; c.f = f;
  return (unsigned short)((c.u + 0x7FFFu + ((c.u >> 16) & 1u)) >> 16);
}

// Quad-fold transpose: C-layout accs (A0: ch 0-15 = quad*4+r, A1: ch 16-31) ->
// A/B fragment (lane quad Q holds ch = Q*8 + 2j+b in u32 reg j).
// Derivation: ch'=8Q+2j+b -> src m2 = Q>>1, src reg = (2j+b)&3,
// src quad = (2Q + (j>>1)) & 3. 8 bpermute + 4 pack + 4 select. (verified R2)
__device__ __forceinline__ bf16x8 xform(f32x4 A0, f32x4 A1, int ae, int ao, bool hi) {
  int P0 = (int)pack2(A0[0], A0[1]), P1 = (int)pack2(A0[2], A0[3]);
  int P2 = (int)pack2(A1[0], A1[1]), P3 = (int)pack2(A1[2], A1[3]);
  int e0 = __builtin_amdgcn_ds_bpermute(ae, P0);
  int e1 = __builtin_amdgcn_ds_bpermute(ae, P1);
  int e2 = __builtin_amdgcn_ds_bpermute(ae, P2);
  int e3 = __builtin_amdgcn_ds_bpermute(ae, P3);
  int o0 = __builtin_amdgcn_ds_bpermute(ao, P0);
  int o1 = __builtin_amdgcn_ds_bpermute(ao, P1);
  int o2 = __builtin_amdgcn_ds_bpermute(ao, P2);
  int o3 = __builtin_amdgcn_ds_bpermute(ao, P3);
  union { bf16x8 v; int u[4]; } r;
  r.u[0] = hi ? e2 : e0;
  r.u[1] = hi ? e3 : e1;
  r.u[2] = hi ? o2 : o0;
  r.u[3] = hi ? o3 : o1;
  return r.v;
}

// K0: fp32 weights -> bf16, [Wq|Wk|Wv|Wp] each 256x256.
__global__ __launch_bounds__(256) void k0_cvt(const float* __restrict__ w0,
                                              const float* __restrict__ w1,
                                              const float* __restrict__ w2,
                                              const float* __restrict__ w3,
                                              unsigned short* __restrict__ dst) {
  int idx = blockIdx.x * 256 + threadIdx.x;
  const float* s = (blockIdx.y == 0) ? w0 : (blockIdx.y == 1) ? w1 : (blockIdx.y == 2) ? w2 : w3;
  dst[blockIdx.y * 65536 + idx] = f2b(s[idx]);
}

// KA: one window per 256-thread block; wave wv owns heads {2wv, 2wv+1}.
// Attention entirely in registers (bpermute transposes); LDS only for the
// shared X tile / obuf. Two-pass QKV per head to bound register pressure.
__global__ __launch_bounds__(256, 3) void ka_fused(
    const unsigned short* __restrict__ Wall,
    const float* __restrict__ ln_g, const float* __restrict__ ln_b,
    const int* __restrict__ pn, const int* __restrict__ pt,
    const float* __restrict__ bq, const float* __restrict__ bk,
    const float* __restrict__ bv, const float* __restrict__ bp,
    const float* __restrict__ inpt, float* __restrict__ out) {
  extern __shared__ unsigned short lds[];

  const int tid = threadIdx.x;
  const int wv = tid >> 6, lane = tid & 63, quad = lane >> 4, l15 = lane & 15;
  const int w = blockIdx.x;
  const int b = w >> 9, nbb = (w >> 6) & 7, tbb = w & 63;
  const f32x4 z4 = {0.f, 0.f, 0.f, 0.f};

  // bpermute source-lane addresses for the quad-fold (byte units)
  const int ae = ((((quad << 1) & 3) << 4) + l15) << 2;
  const int ao = (((((quad << 1) + 1) & 3) << 4) + l15) << 2;
  const bool hi = lane >= 32;

  // ---- fused gather + LayerNorm -> bf16 X tile (16 rows per wave) ----
  {
    const float4 gg = ((const float4*)ln_g)[lane];
    const float4 bb = ((const float4*)ln_b)[lane];
    #pragma unroll
    for (int ii = 0; ii < 2; ++ii) {
      const int nloc = wv * 2 + ii;
      const int spn = pn[(b << 6) + (nbb << 3) + nloc];
      const float* rowbase = inpt + (size_t)((b << 6) + spn) * 512 * 256;
      float4 v[8];
      #pragma unroll
      for (int i = 0; i < 8; ++i) {
        const int spt = pt[(b << 9) + (tbb << 3) + i];
        v[i] = ((const float4*)(rowbase + (size_t)spt * 256))[lane];
      }
      #pragma unroll
      for (int i = 0; i < 8; ++i) {
        float s = v[i].x + v[i].y + v[i].z + v[i].w;
        float ss = v[i].x * v[i].x + v[i].y * v[i].y + v[i].z * v[i].z + v[i].w * v[i].w;
        #pragma unroll
        for (int m = 1; m < 64; m <<= 1) { s += __shfl_xor(s, m); ss += __shfl_xor(ss, m); }
        const float mean = s * (1.0f / 256.0f);
        const float rs = rsqrtf(ss * (1.0f / 256.0f) - mean * mean + EPS_);
        ushort4 o;
        o.x = f2b((v[i].x - mean) * rs * gg.x + bb.x);
        o.y = f2b((v[i].y - mean) * rs * gg.y + bb.y);
        o.z = f2b((v[i].z - mean) * rs * gg.z + bb.z);
        o.w = f2b((v[i].w - mean) * rs * gg.w + bb.w);
        const int row = nloc * 8 + i;
        *(ushort4*)(lds + swzx(row, lane * 4)) = o;
      }
    }
  }
  __syncthreads();

  const unsigned short* Wq = Wall;
  const unsigned short* Wk = Wall + 65536;
  const unsigned short* Wv_ = Wall + 131072;
  const unsigned short* Wp = Wall + 196608;

  uint2 opk[2][2][4];  // per-head packed O held in regs until obuf barrier

  #pragma unroll
  for (int hh = 0; hh < 2; ++hh) {
    const int h = (wv << 1) + hh;

    // ---- pass 1: K^T = Wk·X^T, V = X·Wv^T -> kf, vf fragments ----
    bf16x8 kf[4], vf[2][2];
    {
      f32x4 ka_[2][4], va[4][2];
      #pragma unroll
      for (int m2 = 0; m2 < 2; ++m2)
        #pragma unroll
        for (int nt = 0; nt < 4; ++nt) { ka_[m2][nt] = z4; va[nt][m2] = z4; }

      __builtin_amdgcn_s_setprio(1);
      #pragma unroll
      for (int ks = 0; ks < 8; ++ks) {
        bf16x8 bx[4];
        #pragma unroll
        for (int nt = 0; nt < 4; ++nt)
          bx[nt] = *(const bf16x8*)(lds + swzx(nt * 16 + l15, ks * 32 + quad * 8));
        #pragma unroll
        for (int m2 = 0; m2 < 2; ++m2) {
          const int wrow = (h * 32 + m2 * 16 + l15) * 256 + ks * 32 + quad * 8;
          bf16x8 wk8 = *(const bf16x8*)(Wk + wrow);
          bf16x8 wv8 = *(const bf16x8*)(Wv_ + wrow);
          #pragma unroll
          for (int nt = 0; nt < 4; ++nt) {
            ka_[m2][nt] = __builtin_amdgcn_mfma_f32_16x16x32_bf16(wk8, bx[nt], ka_[m2][nt], 0, 0, 0);
            va[nt][m2] = __builtin_amdgcn_mfma_f32_16x16x32_bf16(bx[nt], wv8, va[nt][m2], 0, 0, 0);
          }
        }
      }
      __builtin_amdgcn_s_setprio(0);

      #pragma unroll
      for (int m2 = 0; m2 < 2; ++m2) {
        const float4 bk4 = ((const float4*)(bk + h * 32 + m2 * 16))[quad];
        const float bvv = bv[h * 32 + m2 * 16 + l15];
        #pragma unroll
        for (int nt = 0; nt < 4; ++nt) {
          ka_[m2][nt][0] += bk4.x; ka_[m2][nt][1] += bk4.y;
          ka_[m2][nt][2] += bk4.z; ka_[m2][nt][3] += bk4.w;
          va[nt][m2][0] += bvv; va[nt][m2][1] += bvv;
          va[nt][m2][2] += bvv; va[nt][m2][3] += bvv;
        }
      }
      #pragma unroll
      for (int i = 0; i < 4; ++i) kf[i] = xform(ka_[0][i], ka_[1][i], ae, ao, hi);
      #pragma unroll
      for (int kk = 0; kk < 2; ++kk)
        #pragma unroll
        for (int m2 = 0; m2 < 2; ++m2)
          vf[kk][m2] = xform(va[2 * kk][m2], va[2 * kk + 1][m2], ae, ao, hi);
    }

    // ---- pass 2: Q^T = Wq·X^T -> qf fragments ----
    bf16x8 qf[4];
    {
      f32x4 qa[2][4];
      #pragma unroll
      for (int m2 = 0; m2 < 2; ++m2)
        #pragma unroll
        for (int nt = 0; nt < 4; ++nt) qa[m2][nt] = z4;

      __builtin_amdgcn_s_setprio(1);
      #pragma unroll
      for (int ks = 0; ks < 8; ++ks) {
        bf16x8 bx[4];
        #pragma unroll
        for (int nt = 0; nt < 4; ++nt)
          bx[nt] = *(const bf16x8*)(lds + swzx(nt * 16 + l15, ks * 32 + quad * 8));
        #pragma unroll
        for (int m2 = 0; m2 < 2; ++m2) {
          const int wrow = (h * 32 + m2 * 16 + l15) * 256 + ks * 32 + quad * 8;
          bf16x8 wq8 = *(const bf16x8*)(Wq + wrow);
          #pragma unroll
          for (int nt = 0; nt < 4; ++nt)
            qa[m2][nt] = __builtin_amdgcn_mfma_f32_16x16x32_bf16(wq8, bx[nt], qa[m2][nt], 0, 0, 0);
        }
      }
      __builtin_amdgcn_s_setprio(0);

      #pragma unroll
      for (int m2 = 0; m2 < 2; ++m2) {
        const float4 bq4 = ((const float4*)(bq + h * 32 + m2 * 16))[quad];
        #pragma unroll
        for (int nt = 0; nt < 4; ++nt) {
          qa[m2][nt][0] = (qa[m2][nt][0] + bq4.x) * QSC;
          qa[m2][nt][1] = (qa[m2][nt][1] + bq4.y) * QSC;
          qa[m2][nt][2] = (qa[m2][nt][2] + bq4.z) * QSC;
          qa[m2][nt][3] = (qa[m2][nt][3] + bq4.w) * QSC;
        }
      }
      #pragma unroll
      for (int i = 0; i < 4; ++i) qf[i] = xform(qa[0][i], qa[1][i], ae, ao, hi);
    }

    // ---- S^T = k·q^T, exp2, pack P-hat fragments (normalization deferred) ----
    float tot[4] = {0.f, 0.f, 0.f, 0.f};
    bf16x8 pb[2][4];
    #pragma unroll
    for (int kk = 0; kk < 2; ++kk)
      #pragma unroll
      for (int ntq = 0; ntq < 4; ++ntq) {
        f32x4 s0 = __builtin_amdgcn_mfma_f32_16x16x32_bf16(kf[2 * kk], qf[ntq], z4, 0, 0, 0);
        f32x4 s1 = __builtin_amdgcn_mfma_f32_16x16x32_bf16(kf[2 * kk + 1], qf[ntq], z4, 0, 0, 0);
        #pragma unroll
        for (int r = 0; r < 4; ++r) {
          s0[r] = __builtin_amdgcn_exp2f(s0[r]); tot[ntq] += s0[r];
          s1[r] = __builtin_amdgcn_exp2f(s1[r]); tot[ntq] += s1[r];
        }
        pb[kk][ntq] = xform(s0, s1, ae, ao, hi);
      }
    float inv[4];
    #pragma unroll
    for (int ntq = 0; ntq < 4; ++ntq) {
      float t = tot[ntq];
      t += __shfl_xor(t, 16);
      t += __shfl_xor(t, 32);
      inv[ntq] = 1.0f / t;
    }

    // ---- O^T = V^T·P-hat^T, then scale by inv (softmax denominator) ----
    __builtin_amdgcn_s_setprio(1);
    #pragma unroll
    for (int m2 = 0; m2 < 2; ++m2)
      #pragma unroll
      for (int ntq = 0; ntq < 4; ++ntq) {
        f32x4 oa = __builtin_amdgcn_mfma_f32_16x16x32_bf16(vf[0][m2], pb[0][ntq], z4, 0, 0, 0);
        oa = __builtin_amdgcn_mfma_f32_16x16x32_bf16(vf[1][m2], pb[1][ntq], oa, 0, 0, 0);
        oa[0] *= inv[ntq]; oa[1] *= inv[ntq]; oa[2] *= inv[ntq]; oa[3] *= inv[ntq];
        opk[hh][m2][ntq] = pack4(oa);
      }
    __builtin_amdgcn_s_setprio(0);
  }

  __syncthreads();  // all waves done reading X (both heads)
  #pragma unroll
  for (int hh = 0; hh < 2; ++hh)
    #pragma unroll
    for (int m2 = 0; m2 < 2; ++m2)
      #pragma unroll
      for (int ntq = 0; ntq < 4; ++ntq)
        *(uint2*)(lds + swzx(ntq * 16 + l15, ((wv * 2 + hh) * 32 + m2 * 16 + quad * 4))) =
            opk[hh][m2][ntq];
  __syncthreads();  // obuf ready

  // ---- proj^T = Wp·O^T : wave owns out-channels [wv*64, wv*64+64) ----
  f32x4 pacc[4][4];
  #pragma unroll
  for (int m4 = 0; m4 < 4; ++m4)
    #pragma unroll
    for (int nto = 0; nto < 4; ++nto) pacc[m4][nto] = z4;
  __builtin_amdgcn_s_setprio(1);
  #pragma unroll
  for (int ks = 0; ks < 8; ++ks) {
    bf16x8 ob[4];
    #pragma unroll
    for (int nto = 0; nto < 4; ++nto)
      ob[nto] = *(const bf16x8*)(lds + swzx(nto * 16 + l15, ks * 32 + quad * 8));
    #pragma unroll
    for (int m4 = 0; m4 < 4; ++m4) {
      bf16x8 wp8 = *(const bf16x8*)(Wp + (wv * 64 + m4 * 16 + l15) * 256 + ks * 32 + quad * 8);
      #pragma unroll
      for (int nto = 0; nto < 4; ++nto)
        pacc[m4][nto] = __builtin_amdgcn_mfma_f32_16x16x32_bf16(wp8, ob[nto], pacc[m4][nto], 0, 0, 0);
    }
  }
  __builtin_amdgcn_s_setprio(0);

  // ---- epilogue: +bp, residual, float4 scatter (col=tok, row=och) ----
  int toff[4];
  #pragma unroll
  for (int nto = 0; nto < 4; ++nto) {
    const int tok = nto * 16 + l15;
    const int n = (nbb << 3) + (tok >> 3), t = (tbb << 3) + (tok & 7);
    toff[nto] = (((b << 6) + pn[(b << 6) + n]) * 512 + pt[(b << 9) + t]) * 256;
  }
  #pragma unroll
  for (int m4 = 0; m4 < 4; ++m4) {
    float4 bp4 = ((const float4*)(bp + wv * 64 + m4 * 16))[quad];
    #pragma unroll
    for (int nto = 0; nto < 4; ++nto) {
      const int off = toff[nto] + wv * 64 + m4 * 16 + quad * 4;
      float4 iv = *(const float4*)(inpt + off);
      float4 o;
      o.x = iv.x + pacc[m4][nto][0] + bp4.x;
      o.y = iv.y + pacc[m4][nto][1] + bp4.y;
      o.z = iv.z + pacc[m4][nto][2] + bp4.z;
      o.w = iv.w + pacc[m4][nto][3] + bp4.w;
      *(float4*)(out + off) = o;
    }
  }
}

extern "C" void kernel_launch(void* const* d_in, const int* in_sizes, int n_in,
                              void* d_out, int out_size, void* d_ws, size_t ws_size,
                              hipStream_t stream) {
  const float* inpt = (const float*)d_in[0];
  const int* perm_n = (const int*)d_in[1];
  const int* perm_t = (const int*)d_in[2];
  const float* ln_g = (const float*)d_in[3];
  const float* ln_b = (const float*)d_in[4];
  const float* Wq = (const float*)d_in[5];
  const float* bq = (const float*)d_in[6];
  const float* Wk = (const float*)d_in[7];
  const float* bk = (const float*)d_in[8];
  const float* Wv = (const float*)d_in[9];
  const float* bv = (const float*)d_in[10];
  const float* Wp = (const float*)d_in[11];
  const float* bp = (const float*)d_in[12];
  float* out = (float*)d_out;

  // ws: Wall (512 KiB) only
  unsigned short* Wall = (unsigned short*)d_ws;

  (void)hipFuncSetAttribute((const void*)ka_fused,
                            hipFuncAttributeMaxDynamicSharedMemorySize, LDS_BYTES);

  k0_cvt<<<dim3(256, 4), 256, 0, stream>>>(Wq, Wk, Wv, Wp, Wall);
  ka_fused<<<2048, 256, LDS_BYTES, stream>>>(Wall, ln_g, ln_b, perm_n, perm_t,
                                             bq, bk, bv, bp, inpt, out);
}

// Round 5
// 399.333 us; speedup vs baseline: 1.2892x; 1.0266x over previous
//
#include <hip/hip_runtime.h>

typedef __attribute__((ext_vector_type(4))) float f32x4;
typedef __attribute__((ext_vector_type(8))) short bf16x8;

#define EPS_ 1e-5f
// SCALE * log2(e): fold exp -> exp2 into the q scaling
#define QSC 0.25503639409729144f

// LDS: X/obuf [64][256] bf16, XOR-swizzled (16B-slot ^= row&7) = 32 KB. Nothing else.
// 512 threads, wave = one head (short serial chain); two-pass QKV (K,V then Q)
// bounds register pressure (~100 peak) under the (512,4) cap of 128 -> 2 blocks/CU
// = 16 waves/CU. All q/k/P/vT transposes in-register via ds_bpermute quad-fold.
#define LDS_BYTES 32768

__device__ __forceinline__ int swzx(int r, int c) { return r * 256 + (c ^ ((r & 7) << 3)); }

__device__ __forceinline__ unsigned int pack2(float a, float b) {
  union { float f; unsigned int u; } ua, ub;
  ua.f = a; ub.f = b;
  unsigned int ra = (ua.u + 0x7FFFu + ((ua.u >> 16) & 1u)) >> 16;
  unsigned int rb = (ub.u + 0x7FFFu + ((ub.u >> 16) & 1u)) & 0xFFFF0000u;
  return ra | rb;
}
__device__ __forceinline__ uint2 pack4(f32x4 v) {
  uint2 o; o.x = pack2(v[0], v[1]); o.y = pack2(v[2], v[3]); return o;
}
__device__ __forceinline__ unsigned short f2b(float f) {
  union { float f; unsigned int u; } c; c.f = f;
  return (unsigned short)((c.u + 0x7FFFu + ((c.u >> 16) & 1u)) >> 16);
}

// Quad-fold transpose: C-layout accs (A0: ch 0-15 = quad*4+r, A1: ch 16-31) ->
// A/B fragment (lane quad Q holds ch = Q*8 + 2j+b in u32 reg j).
// src m2 = Q>>1, src reg = (2j+b)&3, src quad = (2Q + (j>>1)) & 3.
// 8 bpermute + 4 pack + 4 select. (verified R2/R3)
__device__ __forceinline__ bf16x8 xform(f32x4 A0, f32x4 A1, int ae, int ao, bool hi) {
  int P0 = (int)pack2(A0[0], A0[1]), P1 = (int)pack2(A0[2], A0[3]);
  int P2 = (int)pack2(A1[0], A1[1]), P3 = (int)pack2(A1[2], A1[3]);
  int e0 = __builtin_amdgcn_ds_bpermute(ae, P0);
  int e1 = __builtin_amdgcn_ds_bpermute(ae, P1);
  int e2 = __builtin_amdgcn_ds_bpermute(ae, P2);
  int e3 = __builtin_amdgcn_ds_bpermute(ae, P3);
  int o0 = __builtin_amdgcn_ds_bpermute(ao, P0);
  int o1 = __builtin_amdgcn_ds_bpermute(ao, P1);
  int o2 = __builtin_amdgcn_ds_bpermute(ao, P2);
  int o3 = __builtin_amdgcn_ds_bpermute(ao, P3);
  union { bf16x8 v; int u[4]; } r;
  r.u[0] = hi ? e2 : e0;
  r.u[1] = hi ? e3 : e1;
  r.u[2] = hi ? o2 : o0;
  r.u[3] = hi ? o3 : o1;
  return r.v;
}

// K0: fp32 weights -> bf16, [Wq|Wk|Wv|Wp] each 256x256.
__global__ __launch_bounds__(256) void k0_cvt(const float* __restrict__ w0,
                                              const float* __restrict__ w1,
                                              const float* __restrict__ w2,
                                              const float* __restrict__ w3,
                                              unsigned short* __restrict__ dst) {
  int idx = blockIdx.x * 256 + threadIdx.x;
  const float* s = (blockIdx.y == 0) ? w0 : (blockIdx.y == 1) ? w1 : (blockIdx.y == 2) ? w2 : w3;
  dst[blockIdx.y * 65536 + idx] = f2b(s[idx]);
}

// KA: one window per 512-thread block; wave wv = head wv (short chain).
// Attention entirely in registers (bpermute transposes); LDS only for the
// shared X tile / obuf. Two-pass QKV per head to bound register pressure.
__global__ __launch_bounds__(512, 4) void ka_fused(
    const unsigned short* __restrict__ Wall,
    const float* __restrict__ ln_g, const float* __restrict__ ln_b,
    const int* __restrict__ pn, const int* __restrict__ pt,
    const float* __restrict__ bq, const float* __restrict__ bk,
    const float* __restrict__ bv, const float* __restrict__ bp,
    const float* __restrict__ inpt, float* __restrict__ out) {
  extern __shared__ unsigned short lds[];

  const int tid = threadIdx.x;
  const int wv = tid >> 6, lane = tid & 63, quad = lane >> 4, l15 = lane & 15;
  const int w = blockIdx.x;
  const int b = w >> 9, nbb = (w >> 6) & 7, tbb = w & 63;
  const f32x4 z4 = {0.f, 0.f, 0.f, 0.f};

  // bpermute source-lane addresses for the quad-fold (byte units)
  const int ae = ((((quad << 1) & 3) << 4) + l15) << 2;
  const int ao = (((((quad << 1) + 1) & 3) << 4) + l15) << 2;
  const bool hi = lane >= 32;

  // ---- fused gather + LayerNorm -> bf16 X tile (8 rows per wave, 1 n-row) ----
  {
    const float4 gg = ((const float4*)ln_g)[lane];
    const float4 bb = ((const float4*)ln_b)[lane];
    const int spn = pn[(b << 6) + (nbb << 3) + wv];
    const float* rowbase = inpt + (size_t)((b << 6) + spn) * 512 * 256;
    float4 v[8];
    #pragma unroll
    for (int i = 0; i < 8; ++i) {
      const int spt = pt[(b << 9) + (tbb << 3) + i];
      v[i] = ((const float4*)(rowbase + (size_t)spt * 256))[lane];
    }
    #pragma unroll
    for (int i = 0; i < 8; ++i) {
      float s = v[i].x + v[i].y + v[i].z + v[i].w;
      float ss = v[i].x * v[i].x + v[i].y * v[i].y + v[i].z * v[i].z + v[i].w * v[i].w;
      #pragma unroll
      for (int m = 1; m < 64; m <<= 1) { s += __shfl_xor(s, m); ss += __shfl_xor(ss, m); }
      const float mean = s * (1.0f / 256.0f);
      const float rs = rsqrtf(ss * (1.0f / 256.0f) - mean * mean + EPS_);
      ushort4 o;
      o.x = f2b((v[i].x - mean) * rs * gg.x + bb.x);
      o.y = f2b((v[i].y - mean) * rs * gg.y + bb.y);
      o.z = f2b((v[i].z - mean) * rs * gg.z + bb.z);
      o.w = f2b((v[i].w - mean) * rs * gg.w + bb.w);
      *(ushort4*)(lds + swzx(wv * 8 + i, lane * 4)) = o;
    }
  }
  __syncthreads();

  const unsigned short* Wq = Wall;
  const unsigned short* Wk = Wall + 65536;
  const unsigned short* Wv_ = Wall + 131072;
  const unsigned short* Wp = Wall + 196608;
  const int h = wv;

  // ---- pass 1: K^T = Wk·X^T, V = X·Wv^T -> kf, vf fragments ----
  bf16x8 kf[4], vf[2][2];
  {
    f32x4 ka_[2][4], va[4][2];
    #pragma unroll
    for (int m2 = 0; m2 < 2; ++m2)
      #pragma unroll
      for (int nt = 0; nt < 4; ++nt) { ka_[m2][nt] = z4; va[nt][m2] = z4; }

    __builtin_amdgcn_s_setprio(1);
    #pragma unroll
    for (int ks = 0; ks < 8; ++ks) {
      bf16x8 bx[4];
      #pragma unroll
      for (int nt = 0; nt < 4; ++nt)
        bx[nt] = *(const bf16x8*)(lds + swzx(nt * 16 + l15, ks * 32 + quad * 8));
      #pragma unroll
      for (int m2 = 0; m2 < 2; ++m2) {
        const int wrow = (h * 32 + m2 * 16 + l15) * 256 + ks * 32 + quad * 8;
        bf16x8 wk8 = *(const bf16x8*)(Wk + wrow);
        bf16x8 wv8 = *(const bf16x8*)(Wv_ + wrow);
        #pragma unroll
        for (int nt = 0; nt < 4; ++nt) {
          ka_[m2][nt] = __builtin_amdgcn_mfma_f32_16x16x32_bf16(wk8, bx[nt], ka_[m2][nt], 0, 0, 0);
          va[nt][m2] = __builtin_amdgcn_mfma_f32_16x16x32_bf16(bx[nt], wv8, va[nt][m2], 0, 0, 0);
        }
      }
    }
    __builtin_amdgcn_s_setprio(0);

    #pragma unroll
    for (int m2 = 0; m2 < 2; ++m2) {
      const float4 bk4 = ((const float4*)(bk + h * 32 + m2 * 16))[quad];
      const float bvv = bv[h * 32 + m2 * 16 + l15];
      #pragma unroll
      for (int nt = 0; nt < 4; ++nt) {
        ka_[m2][nt][0] += bk4.x; ka_[m2][nt][1] += bk4.y;
        ka_[m2][nt][2] += bk4.z; ka_[m2][nt][3] += bk4.w;
        va[nt][m2][0] += bvv; va[nt][m2][1] += bvv;
        va[nt][m2][2] += bvv; va[nt][m2][3] += bvv;
      }
    }
    #pragma unroll
    for (int i = 0; i < 4; ++i) kf[i] = xform(ka_[0][i], ka_[1][i], ae, ao, hi);
    #pragma unroll
    for (int kk = 0; kk < 2; ++kk)
      #pragma unroll
      for (int m2 = 0; m2 < 2; ++m2)
        vf[kk][m2] = xform(va[2 * kk][m2], va[2 * kk + 1][m2], ae, ao, hi);
  }

  // ---- pass 2: Q^T = Wq·X^T -> qf fragments ----
  bf16x8 qf[4];
  {
    f32x4 qa[2][4];
    #pragma unroll
    for (int m2 = 0; m2 < 2; ++m2)
      #pragma unroll
      for (int nt = 0; nt < 4; ++nt) qa[m2][nt] = z4;

    __builtin_amdgcn_s_setprio(1);
    #pragma unroll
    for (int ks = 0; ks < 8; ++ks) {
      bf16x8 bx[4];
      #pragma unroll
      for (int nt = 0; nt < 4; ++nt)
        bx[nt] = *(const bf16x8*)(lds + swzx(nt * 16 + l15, ks * 32 + quad * 8));
      #pragma unroll
      for (int m2 = 0; m2 < 2; ++m2) {
        const int wrow = (h * 32 + m2 * 16 + l15) * 256 + ks * 32 + quad * 8;
        bf16x8 wq8 = *(const bf16x8*)(Wq + wrow);
        #pragma unroll
        for (int nt = 0; nt < 4; ++nt)
          qa[m2][nt] = __builtin_amdgcn_mfma_f32_16x16x32_bf16(wq8, bx[nt], qa[m2][nt], 0, 0, 0);
      }
    }
    __builtin_amdgcn_s_setprio(0);

    #pragma unroll
    for (int m2 = 0; m2 < 2; ++m2) {
      const float4 bq4 = ((const float4*)(bq + h * 32 + m2 * 16))[quad];
      #pragma unroll
      for (int nt = 0; nt < 4; ++nt) {
        qa[m2][nt][0] = (qa[m2][nt][0] + bq4.x) * QSC;
        qa[m2][nt][1] = (qa[m2][nt][1] + bq4.y) * QSC;
        qa[m2][nt][2] = (qa[m2][nt][2] + bq4.z) * QSC;
        qa[m2][nt][3] = (qa[m2][nt][3] + bq4.w) * QSC;
      }
    }
    #pragma unroll
    for (int i = 0; i < 4; ++i) qf[i] = xform(qa[0][i], qa[1][i], ae, ao, hi);
  }

  // ---- S^T = k·q^T, exp2, pack P-hat fragments (normalization deferred) ----
  float tot[4] = {0.f, 0.f, 0.f, 0.f};
  bf16x8 pb[2][4];
  #pragma unroll
  for (int kk = 0; kk < 2; ++kk)
    #pragma unroll
    for (int ntq = 0; ntq < 4; ++ntq) {
      f32x4 s0 = __builtin_amdgcn_mfma_f32_16x16x32_bf16(kf[2 * kk], qf[ntq], z4, 0, 0, 0);
      f32x4 s1 = __builtin_amdgcn_mfma_f32_16x16x32_bf16(kf[2 * kk + 1], qf[ntq], z4, 0, 0, 0);
      #pragma unroll
      for (int r = 0; r < 4; ++r) {
        s0[r] = __builtin_amdgcn_exp2f(s0[r]); tot[ntq] += s0[r];
        s1[r] = __builtin_amdgcn_exp2f(s1[r]); tot[ntq] += s1[r];
      }
      pb[kk][ntq] = xform(s0, s1, ae, ao, hi);
    }
  float inv[4];
  #pragma unroll
  for (int ntq = 0; ntq < 4; ++ntq) {
    float t = tot[ntq];
    t += __shfl_xor(t, 16);
    t += __shfl_xor(t, 32);
    inv[ntq] = 1.0f / t;
  }

  // ---- O^T = V^T·P-hat^T, then scale by inv (softmax denominator) ----
  uint2 opk[2][4];
  __builtin_amdgcn_s_setprio(1);
  #pragma unroll
  for (int m2 = 0; m2 < 2; ++m2)
    #pragma unroll
    for (int ntq = 0; ntq < 4; ++ntq) {
      f32x4 oa = __builtin_amdgcn_mfma_f32_16x16x32_bf16(vf[0][m2], pb[0][ntq], z4, 0, 0, 0);
      oa = __builtin_amdgcn_mfma_f32_16x16x32_bf16(vf[1][m2], pb[1][ntq], oa, 0, 0, 0);
      oa[0] *= inv[ntq]; oa[1] *= inv[ntq]; oa[2] *= inv[ntq]; oa[3] *= inv[ntq];
      opk[m2][ntq] = pack4(oa);
    }
  __builtin_amdgcn_s_setprio(0);

  __syncthreads();  // all waves done reading X
  #pragma unroll
  for (int m2 = 0; m2 < 2; ++m2)
    #pragma unroll
    for (int ntq = 0; ntq < 4; ++ntq)
      *(uint2*)(lds + swzx(ntq * 16 + l15, (h * 32 + m2 * 16 + quad * 4))) = opk[m2][ntq];
  __syncthreads();  // obuf ready

  // ---- proj^T = Wp·O^T : wave owns out-channels [wv*32, wv*32+32) ----
  f32x4 pacc[2][4];
  #pragma unroll
  for (int m2 = 0; m2 < 2; ++m2)
    #pragma unroll
    for (int nto = 0; nto < 4; ++nto) pacc[m2][nto] = z4;
  __builtin_amdgcn_s_setprio(1);
  #pragma unroll
  for (int ks = 0; ks < 8; ++ks) {
    bf16x8 ob[4];
    #pragma unroll
    for (int nto = 0; nto < 4; ++nto)
      ob[nto] = *(const bf16x8*)(lds + swzx(nto * 16 + l15, ks * 32 + quad * 8));
    #pragma unroll
    for (int m2 = 0; m2 < 2; ++m2) {
      bf16x8 wp8 = *(const bf16x8*)(Wp + (wv * 32 + m2 * 16 + l15) * 256 + ks * 32 + quad * 8);
      #pragma unroll
      for (int nto = 0; nto < 4; ++nto)
        pacc[m2][nto] = __builtin_amdgcn_mfma_f32_16x16x32_bf16(wp8, ob[nto], pacc[m2][nto], 0, 0, 0);
    }
  }
  __builtin_amdgcn_s_setprio(0);

  // ---- epilogue: +bp, residual, float4 scatter (col=tok, row=och) ----
  int toff[4];
  #pragma unroll
  for (int nto = 0; nto < 4; ++nto) {
    const int tok = nto * 16 + l15;
    const int n = (nbb << 3) + (tok >> 3), t = (tbb << 3) + (tok & 7);
    toff[nto] = (((b << 6) + pn[(b << 6) + n]) * 512 + pt[(b << 9) + t]) * 256;
  }
  #pragma unroll
  for (int m2 = 0; m2 < 2; ++m2) {
    float4 bp4 = ((const float4*)(bp + wv * 32 + m2 * 16))[quad];
    #pragma unroll
    for (int nto = 0; nto < 4; ++nto) {
      const int off = toff[nto] + wv * 32 + m2 * 16 + quad * 4;
      float4 iv = *(const float4*)(inpt + off);
      float4 o;
      o.x = iv.x + pacc[m2][nto][0] + bp4.x;
      o.y = iv.y + pacc[m2][nto][1] + bp4.y;
      o.z = iv.z + pacc[m2][nto][2] + bp4.z;
      o.w = iv.w + pacc[m2][nto][3] + bp4.w;
      *(float4*)(out + off) = o;
    }
  }
}

extern "C" void kernel_launch(void* const* d_in, const int* in_sizes, int n_in,
                              void* d_out, int out_size, void* d_ws, size_t ws_size,
                              hipStream_t stream) {
  const float* inpt = (const float*)d_in[0];
  const int* perm_n = (const int*)d_in[1];
  const int* perm_t = (const int*)d_in[2];
  const float* ln_g = (const float*)d_in[3];
  const float* ln_b = (const float*)d_in[4];
  const float* Wq = (const float*)d_in[5];
  const float* bq = (const float*)d_in[6];
  const float* Wk = (const float*)d_in[7];
  const float* bk = (const float*)d_in[8];
  const float* Wv = (const float*)d_in[9];
  const float* bv = (const float*)d_in[10];
  const float* Wp = (const float*)d_in[11];
  const float* bp = (const float*)d_in[12];
  float* out = (float*)d_out;

  // ws: Wall (512 KiB) only
  unsigned short* Wall = (unsigned short*)d_ws;

  (void)hipFuncSetAttribute((const void*)ka_fused,
                            hipFuncAttributeMaxDynamicSharedMemorySize, LDS_BYTES);

  k0_cvt<<<dim3(256, 4), 256, 0, stream>>>(Wq, Wk, Wv, Wp, Wall);
  ka_fused<<<2048, 512, LDS_BYTES, stream>>>(Wall, ln_g, ln_b, perm_n, perm_t,
                                             bq, bk, bv, bp, inpt, out);
}